// Round 18
// baseline (189.226 us; speedup 1.0000x reference)
//
#include <hip/hip_runtime.h>
#include <hip/hip_bf16.h>
#include <math.h>

// ---------------------------------------------------------------------------
// HyperParamNet — round 18.
// R17 landed: kA 92.6us (f16-dot2 halo, LDS 18.4KB, VGPR 64+32AGPR=96,
// no spill at lb(256,4)), total 119.6us. Still latency-bound (VALUBusy 44%,
// Occ 40%, no pipe saturated).
// This round (single change): kA lb(256,4) -> lb(256,5). Unlike R8/R13,
// this fits WITHOUT register squeeze: 96 regs x 5 waves/SIMD = 480 <= 512;
// LDS 18.4KB x 5 = 92KB <= 160KB. Tripwire: WRITE_SIZE spike = spill.
// kB / kC / kInit byte-identical to R17.
// ---------------------------------------------------------------------------

using s16x8 = __attribute__((ext_vector_type(8))) short;
using f32x4 = __attribute__((ext_vector_type(4))) float;
using f32x2 = __attribute__((ext_vector_type(2))) float;

__device__ __forceinline__ float leaky(float x) {
    return x >= 0.f ? x : 0.01f * x;
}

__device__ __forceinline__ unsigned short f2bf(float f) {
    unsigned x = __float_as_uint(f);
    return (unsigned short)((x + 0x7FFFu + ((x >> 16) & 1u)) >> 16);
}

__device__ __forceinline__ unsigned pk16(float a, float b) {
    unsigned r;
    asm("v_cvt_pkrtz_f16_f32 %0, %1, %2" : "=v"(r) : "v"(a), "v"(b));
    return r;
}

__device__ __forceinline__ float dot2(unsigned a, unsigned b, float c) {
    float r;
    asm("v_dot2_f32_f16 %0, %1, %2, %3" : "=v"(r) : "v"(a), "v"(b), "v"(c));
    return r;
}

// ---------------------------------------------------------------------------
// kInit: zero ta accumulators; transpose bw1 (kC ph2); pack bw2 bf16 q-major
// (kC ph3 MFMA); pack conv1 W as f16-pair dwords + conv2 W bf16 (kA).
// ---------------------------------------------------------------------------
__global__ void kInit(float* __restrict__ sums, unsigned* __restrict__ maxu,
                      const float* __restrict__ bw1, const float* __restrict__ bw2,
                      const float* __restrict__ fw1, const float* __restrict__ fw2,
                      float* __restrict__ wT1g, short* __restrict__ wsW2b,
                      unsigned* __restrict__ wsW1, short* __restrict__ wsW) {
    int t = threadIdx.x;   // 256
    sums[t] = 0.f;
    maxu[t] = 0u;
    for (int i = t; i < 288; i += 256) {      // wT1g[(ic*9+k)*16 + o]
        int o = i & 15, rest = i >> 4;
        int ic = rest / 9, k = rest - ic * 9;
        wT1g[i] = bw1[(o * 2 + ic) * 9 + k];
    }
    // bw2 bf16, q-major K-pad: wsW2b[o*160 + q*16 + ic], q<9 valid
    for (int i = t; i < 2560; i += 256) {
        int o = i / 160, kp = i - o * 160;
        int q = kp >> 4, ic = kp & 15;
        wsW2b[i] = (q < 9) ? (short)f2bf(bw2[(o * 16 + ic) * 9 + q]) : (short)0;
    }
    // conv1 weights: wsW1[(c4*9+q)*4 + cl] = f16-pair (wy, wm), ch=4*c4+cl
    for (int i = t; i < 1008; i += 256) {
        int c4 = i / 36, rem = i - c4 * 36;
        int q = rem >> 2, cl = rem & 3;
        int ch = c4 * 4 + cl;
        wsW1[i] = pk16(fw1[ch * 18 + q], fw1[ch * 18 + 9 + q]);
    }
    // conv2 weights: bf16 [64][128], K zero-padded 112..127
    for (int i = t; i < 8192; i += 256) {
        int o = i >> 7, k = i & 127;
        wsW[i] = (k < 112) ? (short)f2bf(fw2[o * 112 + k]) : (short)0;
    }
}

// ---------------------------------------------------------------------------
// kA: fused conv1(grouped 3x3, f16 dot2) + conv2(1x1, MFMA) + xc + ta reduce.
// Flat grid 4096, XCD-chunked swizzle (XCD k owns batch k). Block 256 =
// 4 waves; wave wv owns rows 2wv..2wv+1, lane (col,lq): pixel col, k-slice lq.
// Halo LDS: ONE dword/pixel = packed f16(y,m); col-major stride 11, dbuf.
// lb(256,5): 96 regs x 5 = 480 <= 512, LDS 92KB <= 160KB — fits w/o squeeze.
// ---------------------------------------------------------------------------
__global__ __launch_bounds__(256, 5) void kA(
    const float* __restrict__ y, const float* __restrict__ mask,
    const float* __restrict__ fb1, const float* __restrict__ fb2,
    const unsigned* __restrict__ wsW1, const short* __restrict__ wsW,
    float* __restrict__ xc, float* __restrict__ sums, unsigned* __restrict__ maxu)
{
    __shared__ unsigned shH[2][1584];            // packed halo dbuf 12672B
    __shared__ __align__(16) unsigned w1p[1008]; // conv1 W f16-pair  4032B
    __shared__ __align__(16) float  fbl[112];    // conv1 bias         448B
    __shared__ float  red[4 * 32 * 2];           // ta partials       1024B

    // ---- XCD-chunked swizzle (bijective: 4096 % 8 == 0) ----
    const int orig = blockIdx.x;
    const int wg   = (orig & 7) * 512 + (orig >> 3);
    const int b    = wg >> 9;
    const int h0   = ((wg >> 4) & 31) << 3;
    const int w0   = (wg & 15) << 4;

    const int tid = threadIdx.x;
    const int wv = tid >> 6, ln = tid & 63;
    const int col = ln & 15, lq = ln >> 4;

    // ---- weight staging: plain copies (packed by kInit) ----
    #pragma unroll
    for (int j = 0; j < 4; ++j) {
        int i = tid + j * 256;
        if (i < 1008) w1p[i] = wsW1[i];
    }
    if (tid < 112) fbl[tid] = fb1[tid];

    // ---- staging slots: ROW-major global walk, col-major LDS (stride 11) ----
    int  sOff[7], sLds[7];
    bool sOK[7];
    #pragma unroll
    for (int j = 0; j < 7; ++j) {
        const int i = tid + j * 256;
        int gl = i / 180, rem = i - gl * 180;
        int r = rem / 18, c = rem - r * 18;      // row-major walk (coalesced)
        int gh = h0 + r - 1, gw = w0 + c - 1;
        sOK[j]  = (i < 1440) && ((unsigned)gh < 256u) && ((unsigned)gw < 256u);
        sOff[j] = ((b * 28 + gl) << 16) + (gh << 8) + gw;
        sLds[j] = gl * 198 + c * 11 + r;         // col-major store, stride 11
    }

    // ---- prologue: load + publish chunk 0 into buffer 0 ----
    float2 pf[7];
    #pragma unroll
    for (int j = 0; j < 7; ++j) {
        pf[j] = make_float2(0.f, 0.f);
        if (sOK[j]) {
            size_t o = (size_t)sOff[j];
            pf[j].x = y[o];
            pf[j].y = mask[o];
        }
    }
    #pragma unroll
    for (int j = 0; j < 7; ++j) {
        if (tid + j * 256 < 1440)
            shH[0][sLds[j]] = pk16(pf[j].x, pf[j].y);
    }

    // ---- C accumulators, init with conv2 bias ----
    f32x4 acc[2][4];   // [pg][t]
    #pragma unroll
    for (int t = 0; t < 4; ++t) {
        #pragma unroll
        for (int r = 0; r < 4; ++r) {
            float bv = fb2[t * 16 + lq * 4 + r];
            acc[0][t][r] = bv;
            acc[1][t][r] = bv;
        }
    }
    __syncthreads();   // chunk-0 halo + weights visible

    // ---- K-chunk loop, double-buffered: 1 barrier per chunk ----
    #pragma unroll 1
    for (int s = 0; s < 4; ++s) {
        const int cur = s & 1;

        // issue next chunk's loads NOW (latency hides under compute below)
        const int TOTn = (s == 2) ? 720 : 1440;
        if (s < 3) {
            const int chAdd = ((s + 1) * 8) << 16;
            #pragma unroll
            for (int j = 0; j < 7; ++j) {
                pf[j] = make_float2(0.f, 0.f);
                if (sOK[j] && (tid + j * 256) < TOTn) {
                    size_t o = (size_t)(sOff[j] + chAdd);
                    pf[j].x = y[o];
                    pf[j].y = mask[o];
                }
            }
        }

        // A-fragments direct from global (L2-resident)
        s16x8 A[4];
        #pragma unroll
        for (int t = 0; t < 4; ++t)
            A[t] = *(const s16x8*)&wsW[(t * 16 + col) * 128 + s * 32 + lq * 8];

        // ---- conv1 -> B-fragments (f16 dot2, f32 accum) ----
        unsigned Bu[2][4] = {{0u,0u,0u,0u},{0u,0u,0u,0u}};

        if (s < 3 || lq < 2) {             // s=3, lq>=2 -> channels >=112
            #pragma unroll
            for (int gidx = 0; gidx < 2; ++gidx) {
                const int gl = 2 * lq + gidx;      // local group 0..7
                const int c4 = s * 8 + gl;         // global channel-quad
                const unsigned* hb = &shH[cur][gl * 198 + col * 11 + 2 * wv];
                unsigned hl[3][4];                 // [col][row] packed (y,m)
                #pragma unroll
                for (int cc = 0; cc < 3; ++cc)
                    #pragma unroll
                    for (int rr = 0; rr < 4; ++rr)
                        hl[cc][rr] = hb[cc * 11 + rr];

                const f32x4 bias4 = *(const f32x4*)&fbl[c4 * 4];
                float a[4][2];
                #pragma unroll
                for (int jj = 0; jj < 4; ++jj) {
                    a[jj][0] = bias4[jj];
                    a[jj][1] = bias4[jj];
                }
                const uint4* wq4 = (const uint4*)&w1p[c4 * 36];
                #pragma unroll
                for (int q = 0; q < 9; ++q) {
                    const uint4 w = wq4[q];        // 4 channels' (wy,wm) pairs
                    const int dy = q / 3, dx = q % 3;
                    const unsigned h0p = hl[dx][dy];
                    const unsigned h1p = hl[dx][dy + 1];
                    a[0][0] = dot2(h0p, w.x, a[0][0]);
                    a[0][1] = dot2(h1p, w.x, a[0][1]);
                    a[1][0] = dot2(h0p, w.y, a[1][0]);
                    a[1][1] = dot2(h1p, w.y, a[1][1]);
                    a[2][0] = dot2(h0p, w.z, a[2][0]);
                    a[2][1] = dot2(h1p, w.z, a[2][1]);
                    a[3][0] = dot2(h0p, w.w, a[3][0]);
                    a[3][1] = dot2(h1p, w.w, a[3][1]);
                }
                #pragma unroll
                for (int pg = 0; pg < 2; ++pg) {
                    const float r0 = fmaxf(a[0][pg], 0.f);
                    const float r1 = fmaxf(a[1][pg], 0.f);
                    const float r2 = fmaxf(a[2][pg], 0.f);
                    const float r3 = fmaxf(a[3][pg], 0.f);
                    unsigned wlo, whi;
                    asm("v_cvt_pk_bf16_f32 %0, %1, %2" : "=v"(wlo) : "v"(r0), "v"(r1));
                    asm("v_cvt_pk_bf16_f32 %0, %1, %2" : "=v"(whi) : "v"(r2), "v"(r3));
                    Bu[pg][gidx * 2 + 0] = wlo;
                    Bu[pg][gidx * 2 + 1] = whi;
                }
            }
        }

        s16x8 Bf[2];
        #pragma unroll
        for (int pg = 0; pg < 2; ++pg) {
            union { unsigned u[4]; s16x8 v; } cvt;
            cvt.u[0] = Bu[pg][0]; cvt.u[1] = Bu[pg][1];
            cvt.u[2] = Bu[pg][2]; cvt.u[3] = Bu[pg][3];
            Bf[pg] = cvt.v;
        }

        #pragma unroll
        for (int pg = 0; pg < 2; ++pg)
            #pragma unroll
            for (int t = 0; t < 4; ++t)
                acc[pg][t] = __builtin_amdgcn_mfma_f32_16x16x32_bf16(
                                 A[t], Bf[pg], acc[pg][t], 0, 0, 0);

        // ---- publish prefetched chunk into the OTHER buffer ----
        if (s < 3) {
            #pragma unroll
            for (int j = 0; j < 7; ++j) {
                if (tid + j * 256 < TOTn)
                    shH[cur ^ 1][sLds[j]] = pk16(pf[j].x, pf[j].y);
            }
            __syncthreads();   // next-chunk halo visible to all waves
        }
    }

    // ---- epilogue (proven rounds 3-17) ----
    float* xc0 = xc + (((size_t)b * 2) << 16);
    float* xc1 = xc0 + 65536;

    float run_s[2][4], run_m[2][4];
    #pragma unroll
    for (int t = 0; t < 2; ++t)
        #pragma unroll
        for (int r = 0; r < 4; ++r) { run_s[t][r] = 0.f; run_m[t][r] = -3.4e38f; }

    #pragma unroll
    for (int pg = 0; pg < 2; ++pg) {
        float m8 = -3.4e38f, s8 = 0.f;
        #pragma unroll
        for (int t = 2; t < 4; ++t)
            #pragma unroll
            for (int r = 0; r < 4; ++r) {
                float v = acc[pg][t][r];
                m8 = fmaxf(m8, v); s8 += v;
            }
        m8 = fmaxf(m8, __shfl_xor(m8, 16));
        m8 = fmaxf(m8, __shfl_xor(m8, 32));
        s8 += __shfl_xor(s8, 16);
        s8 += __shfl_xor(s8, 32);
        if (ln < 16) {
            int row = h0 + 2 * wv + pg;
            xc0[(row << 8) + w0 + ln] = m8;
            xc1[(row << 8) + w0 + ln] = s8 * (1.f / 32.f);
        }
        #pragma unroll
        for (int t = 0; t < 2; ++t)
            #pragma unroll
            for (int r = 0; r < 4; ++r) {
                float v = acc[pg][t][r];
                run_s[t][r] += v;
                run_m[t][r] = fmaxf(run_m[t][r], v);
            }
    }

    #pragma unroll
    for (int t = 0; t < 2; ++t)
        #pragma unroll
        for (int r = 0; r < 4; ++r) {
            float s = run_s[t][r], m = run_m[t][r];
            #pragma unroll
            for (int off = 1; off < 16; off <<= 1) {
                s += __shfl_xor(s, off);
                m = fmaxf(m, __shfl_xor(m, off));
            }
            if (col == 0) {
                int ch = t * 16 + lq * 4 + r;
                red[(wv * 32 + ch) * 2 + 0] = s;
                red[(wv * 32 + ch) * 2 + 1] = m;
            }
        }
    __syncthreads();
    if (tid < 32) {
        float s = red[tid*2] + red[(32+tid)*2] + red[(64+tid)*2] + red[(96+tid)*2];
        float m = fmaxf(fmaxf(red[tid*2+1], red[(32+tid)*2+1]),
                        fmaxf(red[(64+tid)*2+1], red[(96+tid)*2+1]));
        atomicAdd(&sums[b*32 + tid], s);
        unsigned ub  = __float_as_uint(m);
        unsigned key = (ub & 0x80000000u) ? ~ub : (ub | 0x80000000u);
        atomicMax(&maxu[b*32 + tid], key);
    }
}

// ---------------------------------------------------------------------------
// Kernel B: finish ta mean/max, run pgm MLP on both, alpha = sum.
// ---------------------------------------------------------------------------
__global__ __launch_bounds__(256) void kB(
    const float* __restrict__ sums, const unsigned* __restrict__ maxu,
    const float* __restrict__ aw1, const float* __restrict__ ab1,
    const float* __restrict__ aw2, const float* __restrict__ ab2,
    const float* __restrict__ aw3, const float* __restrict__ ab3,
    float* __restrict__ out)
{
    __shared__ float xa[8][32], xm[8][32], h1a[8][32], h1m[8][32];
    const int tid = threadIdx.x;
    const int b = tid >> 5, i = tid & 31;

    xa[b][i] = sums[b*32 + i] * (1.f/65536.f);
    unsigned u = maxu[b*32 + i];
    unsigned bits = (u & 0x80000000u) ? (u ^ 0x80000000u) : ~u;
    xm[b][i] = __uint_as_float(bits);
    __syncthreads();

    float sa = ab1[i], sm = ab1[i];
    #pragma unroll
    for (int j = 0; j < 32; ++j) {
        float w = aw1[i*32 + j];
        sa += w * xa[b][j]; sm += w * xm[b][j];
    }
    __syncthreads();
    h1a[b][i] = leaky(sa); h1m[b][i] = leaky(sm);
    __syncthreads();

    sa = ab2[i]; sm = ab2[i];
    #pragma unroll
    for (int j = 0; j < 32; ++j) {
        float w = aw2[i*32 + j];
        sa += w * h1a[b][j]; sm += w * h1m[b][j];
    }
    float h2a = leaky(sa), h2m = leaky(sm);

    float pa = aw3[i] * h2a, pm = aw3[i] * h2m;
    #pragma unroll
    for (int off = 16; off > 0; off >>= 1) {
        pa += __shfl_xor(pa, off);
        pm += __shfl_xor(pm, off);
    }
    if (i == 0) {
        float za = fmaxf(pa + ab3[0], 0.f) + 1e-6f;
        float zm = fmaxf(pm + ab3[0], 0.f) + 1e-6f;
        out[b] = za + zm;
    }
}

// ---------------------------------------------------------------------------
// kC: fused beta chain; phase 3 MFMA (R15-proven). XCD-chunked swizzle
// matching kA's batch->XCD mapping.
// ---------------------------------------------------------------------------
__global__ __launch_bounds__(256, 3) void kC(
    const float* __restrict__ xc,
    const float* __restrict__ wT1g, const float* __restrict__ bb1,
    const short* __restrict__ wsW2b, const float* __restrict__ bb2,
    const float* __restrict__ bw3, const float* __restrict__ bb3,
    float* __restrict__ betaout)
{
    __shared__ float shX[2 * 484];     // xc halo [2][22][22]    3872B
    __shared__ float shB1[16 * 400];   // b1 [o][20][20]        25600B
    __shared__ float shB2[16 * 324];   // b2 [o][18][18]        20736B

    // ---- XCD-chunked swizzle (bijective: 2048 % 8 == 0) ----
    const int orig = blockIdx.x;
    const int wg   = (orig & 7) * 256 + (orig >> 3);
    const int b    = wg >> 8;
    const int h0   = ((wg >> 4) & 15) << 4;
    const int w0   = (wg & 15) << 4;
    const int tid = threadIdx.x;
    const int ln  = tid & 63, wv = tid >> 6;
    const int col = ln & 15,  lq = ln >> 4;

    for (int i = tid; i < 968; i += 256) {
        int ch = i / 484, rem = i - ch * 484;
        int r = rem / 22, c = rem - r * 22;
        int gh = h0 + r - 3, gw = w0 + c - 3;
        float v = 0.f;
        if ((unsigned)gh < 256u && (unsigned)gw < 256u)
            v = xc[(((size_t)b * 2 + ch) << 16) + (gh << 8) + gw];
        shX[i] = v;
    }
    __syncthreads();

    // ---- phase 2: b1 = leaky(conv3x3(xc)) on 20x20 (VALU, proven) ----
    const f32x4 bias1_0 = *(const f32x4*)&bb1[0];
    const f32x4 bias1_1 = *(const f32x4*)&bb1[4];
    const f32x4 bias1_2 = *(const f32x4*)&bb1[8];
    const f32x4 bias1_3 = *(const f32x4*)&bb1[12];
    #pragma unroll 1
    for (int p = tid; p < 400; p += 256) {
        int r1 = p / 20, c1 = p - r1 * 20;
        f32x4 a0 = bias1_0, a1 = bias1_1, a2 = bias1_2, a3 = bias1_3;
        #pragma unroll
        for (int ic = 0; ic < 2; ++ic)
            #pragma unroll
            for (int k = 0; k < 9; ++k) {
                float v = shX[ic * 484 + (r1 + k / 3) * 22 + (c1 + k % 3)];
                const f32x4* wp = (const f32x4*)&wT1g[(ic * 9 + k) << 4];
                a0 += wp[0] * v; a1 += wp[1] * v;
                a2 += wp[2] * v; a3 += wp[3] * v;
            }
        int gh = h0 - 2 + r1, gw = w0 - 2 + c1;
        if (((unsigned)gh < 256u) && ((unsigned)gw < 256u)) {
            shB1[ 0*400+p]=leaky(a0[0]); shB1[ 1*400+p]=leaky(a0[1]);
            shB1[ 2*400+p]=leaky(a0[2]); shB1[ 3*400+p]=leaky(a0[3]);
            shB1[ 4*400+p]=leaky(a1[0]); shB1[ 5*400+p]=leaky(a1[1]);
            shB1[ 6*400+p]=leaky(a1[2]); shB1[ 7*400+p]=leaky(a1[3]);
            shB1[ 8*400+p]=leaky(a2[0]); shB1[ 9*400+p]=leaky(a2[1]);
            shB1[10*400+p]=leaky(a2[2]); shB1[11*400+p]=leaky(a2[3]);
            shB1[12*400+p]=leaky(a3[0]); shB1[13*400+p]=leaky(a3[1]);
            shB1[14*400+p]=leaky(a3[2]); shB1[15*400+p]=leaky(a3[3]);
        } else {
            #pragma unroll
            for (int o = 0; o < 16; ++o) shB1[o*400+p] = 0.f;
        }
    }
    __syncthreads();

    // ---- phase 3 (MFMA): b2 = leaky(conv3x3(b1)), 16->16, K'=160 ----
    {
        s16x8 A3[5];
        #pragma unroll
        for (int s = 0; s < 5; ++s)
            A3[s] = *(const s16x8*)&wsW2b[col * 160 + s * 32 + lq * 8];
        f32x4 bias3;
        #pragma unroll
        for (int r = 0; r < 4; ++r) bias3[r] = bb2[lq * 4 + r];

        #pragma unroll 1
        for (int g = wv; g < 21; g += 4) {
            const int p  = g * 16 + col;
            const int pc = (p < 324) ? p : 0;
            const int r2 = (pc * 3641) >> 16;      // /18
            const int c2 = pc - r2 * 18;
            const int pbase = r2 * 20 + c2;
            f32x4 c3 = bias3;
            #pragma unroll
            for (int s = 0; s < 5; ++s) {
                const int q = 2 * s + (lq >> 1);
                s16x8 B3;
                if (s == 4 && lq >= 2) {
                    #pragma unroll
                    for (int j = 0; j < 8; ++j) B3[j] = 0;
                } else {
                    const int dy = (q * 11) >> 5;  // q/3 for q<9
                    const int dx = q - 3 * dy;
                    const float* src = &shB1[((lq & 1) * 8) * 400
                                             + pbase + dy * 20 + dx];
                    float f0 = src[0],    f1 = src[400],  f2 = src[800];
                    float f3 = src[1200], f4 = src[1600], f5 = src[2000];
                    float f6 = src[2400], f7 = src[2800];
                    unsigned u0, u1, u2, u3;
                    asm("v_cvt_pk_bf16_f32 %0, %1, %2" : "=v"(u0) : "v"(f0), "v"(f1));
                    asm("v_cvt_pk_bf16_f32 %0, %1, %2" : "=v"(u1) : "v"(f2), "v"(f3));
                    asm("v_cvt_pk_bf16_f32 %0, %1, %2" : "=v"(u2) : "v"(f4), "v"(f5));
                    asm("v_cvt_pk_bf16_f32 %0, %1, %2" : "=v"(u3) : "v"(f6), "v"(f7));
                    union { unsigned u[4]; s16x8 v; } cv;
                    cv.u[0] = u0; cv.u[1] = u1; cv.u[2] = u2; cv.u[3] = u3;
                    B3 = cv.v;
                }
                c3 = __builtin_amdgcn_mfma_f32_16x16x32_bf16(A3[s], B3, c3, 0, 0, 0);
            }
            if (p < 324) {
                const int gh = h0 - 1 + r2, gw = w0 - 1 + c2;
                const bool vimg = ((unsigned)gh < 256u) && ((unsigned)gw < 256u);
                #pragma unroll
                for (int r = 0; r < 4; ++r)
                    shB2[(lq * 4 + r) * 324 + p] = vimg ? leaky(c3[r]) : 0.f;
            }
        }
    }
    __syncthreads();

    // ---- phase 4: beta = sigmoid(conv3x3(b2)) on the 16x16 tile ----
    {
        int r3 = tid >> 4, c3 = tid & 15;
        float a = bb3[0];
        #pragma unroll 4
        for (int ic = 0; ic < 16; ++ic)
            #pragma unroll
            for (int k = 0; k < 9; ++k)
                a += bw3[ic * 9 + k]
                     * shB2[ic * 324 + (r3 + k / 3) * 18 + (c3 + k % 3)];
        betaout[((size_t)b << 16) + ((h0 + r3) << 8) + (w0 + c3)]
            = 1.f / (1.f + expf(-a));
    }
}

// ---------------------------------------------------------------------------
extern "C" void kernel_launch(void* const* d_in, const int* in_sizes, int n_in,
                              void* d_out, int out_size, void* d_ws, size_t ws_size,
                              hipStream_t stream) {
    const float* y    = (const float*)d_in[0];
    const float* mask = (const float*)d_in[1];
    const float* fw1  = (const float*)d_in[2];
    const float* fb1  = (const float*)d_in[3];
    const float* fw2  = (const float*)d_in[4];
    const float* fb2  = (const float*)d_in[5];
    const float* aw1  = (const float*)d_in[6];
    const float* ab1  = (const float*)d_in[7];
    const float* aw2  = (const float*)d_in[8];
    const float* ab2  = (const float*)d_in[9];
    const float* aw3  = (const float*)d_in[10];
    const float* ab3  = (const float*)d_in[11];
    const float* bw1  = (const float*)d_in[12];
    const float* bb1  = (const float*)d_in[13];
    const float* bw2  = (const float*)d_in[14];
    const float* bb2  = (const float*)d_in[15];
    const float* bw3  = (const float*)d_in[16];
    const float* bb3  = (const float*)d_in[17];
    float* out = (float*)d_out;

    char* ws = (char*)d_ws;
    float*    sums  = (float*)ws;                // 1 KB
    unsigned* maxu  = (unsigned*)(ws + 1024);    // 1 KB
    float*    wT1g  = (float*)(ws + 2048);       // 1152 B
    short*    wsW2b = (short*)(ws + 3200);       // 5120 B (ends 8320)
    unsigned* wsW1  = (unsigned*)(ws + 12416);   // 4032 B (ends 16448)
    short*    wsW   = (short*)(ws + 20480);      // 16384 B (ends 36864)
    float*    xc    = (float*)(ws + 65536);      // 4 MB

    kInit<<<1, 256, 0, stream>>>(sums, maxu, bw1, bw2, fw1, fw2,
                                 wT1g, wsW2b, wsW1, wsW);
    kA<<<4096, 256, 0, stream>>>(y, mask, fb1, fb2, wsW1, wsW,
                                 xc, sums, maxu);
    kB<<<1, 256, 0, stream>>>(sums, maxu, aw1, ab1, aw2, ab2, aw3, ab3, out);
    kC<<<2048, 256, 0, stream>>>(xc, wT1g, bb1, wsW2b, bb2, bw3, bb3,
                                 out + 8);
}

// Round 19
// 121.045 us; speedup vs baseline: 1.5633x; 1.5633x over previous
//
#include <hip/hip_runtime.h>
#include <hip/hip_bf16.h>
#include <math.h>

// ---------------------------------------------------------------------------
// HyperParamNet — round 19: exact revert to R17 (best: 119.6us).
// R18 proved (3rd time: R8, R13, R18) that any launch-bounds > 4 waves/SIMD
// squeezes this kernel below its ~96-reg true need -> spill (VGPR 48,
// WRITE 281MB, kA 214us). lb(256,4) is the occupancy optimum.
// Configuration: kA = f16-dot2 halo (1 dword/pixel), double-buffered
// staging, XCD-chunked swizzle, weights prepacked in ws by kInit, MFMA
// conv2; kC = LDS-fused beta chain with MFMA phase 3 + XCD swizzle.
// ---------------------------------------------------------------------------

using s16x8 = __attribute__((ext_vector_type(8))) short;
using f32x4 = __attribute__((ext_vector_type(4))) float;
using f32x2 = __attribute__((ext_vector_type(2))) float;

__device__ __forceinline__ float leaky(float x) {
    return x >= 0.f ? x : 0.01f * x;
}

__device__ __forceinline__ unsigned short f2bf(float f) {
    unsigned x = __float_as_uint(f);
    return (unsigned short)((x + 0x7FFFu + ((x >> 16) & 1u)) >> 16);
}

__device__ __forceinline__ unsigned pk16(float a, float b) {
    unsigned r;
    asm("v_cvt_pkrtz_f16_f32 %0, %1, %2" : "=v"(r) : "v"(a), "v"(b));
    return r;
}

__device__ __forceinline__ float dot2(unsigned a, unsigned b, float c) {
    float r;
    asm("v_dot2_f32_f16 %0, %1, %2, %3" : "=v"(r) : "v"(a), "v"(b), "v"(c));
    return r;
}

// ---------------------------------------------------------------------------
// kInit: zero ta accumulators; transpose bw1 (kC ph2); pack bw2 bf16 q-major
// (kC ph3 MFMA); pack conv1 W as f16-pair dwords + conv2 W bf16 (kA).
// ---------------------------------------------------------------------------
__global__ void kInit(float* __restrict__ sums, unsigned* __restrict__ maxu,
                      const float* __restrict__ bw1, const float* __restrict__ bw2,
                      const float* __restrict__ fw1, const float* __restrict__ fw2,
                      float* __restrict__ wT1g, short* __restrict__ wsW2b,
                      unsigned* __restrict__ wsW1, short* __restrict__ wsW) {
    int t = threadIdx.x;   // 256
    sums[t] = 0.f;
    maxu[t] = 0u;
    for (int i = t; i < 288; i += 256) {      // wT1g[(ic*9+k)*16 + o]
        int o = i & 15, rest = i >> 4;
        int ic = rest / 9, k = rest - ic * 9;
        wT1g[i] = bw1[(o * 2 + ic) * 9 + k];
    }
    // bw2 bf16, q-major K-pad: wsW2b[o*160 + q*16 + ic], q<9 valid
    for (int i = t; i < 2560; i += 256) {
        int o = i / 160, kp = i - o * 160;
        int q = kp >> 4, ic = kp & 15;
        wsW2b[i] = (q < 9) ? (short)f2bf(bw2[(o * 16 + ic) * 9 + q]) : (short)0;
    }
    // conv1 weights: wsW1[(c4*9+q)*4 + cl] = f16-pair (wy, wm), ch=4*c4+cl
    for (int i = t; i < 1008; i += 256) {
        int c4 = i / 36, rem = i - c4 * 36;
        int q = rem >> 2, cl = rem & 3;
        int ch = c4 * 4 + cl;
        wsW1[i] = pk16(fw1[ch * 18 + q], fw1[ch * 18 + 9 + q]);
    }
    // conv2 weights: bf16 [64][128], K zero-padded 112..127
    for (int i = t; i < 8192; i += 256) {
        int o = i >> 7, k = i & 127;
        wsW[i] = (k < 112) ? (short)f2bf(fw2[o * 112 + k]) : (short)0;
    }
}

// ---------------------------------------------------------------------------
// kA: fused conv1(grouped 3x3, f16 dot2) + conv2(1x1, MFMA) + xc + ta reduce.
// Flat grid 4096, XCD-chunked swizzle (XCD k owns batch k). Block 256 =
// 4 waves; wave wv owns rows 2wv..2wv+1, lane (col,lq): pixel col, k-slice lq.
// Halo LDS: ONE dword/pixel = packed f16(y,m); col-major stride 11, dbuf.
// lb(256,4): R8/R13/R18 all prove >4 waves/SIMD spills this kernel.
// ---------------------------------------------------------------------------
__global__ __launch_bounds__(256, 4) void kA(
    const float* __restrict__ y, const float* __restrict__ mask,
    const float* __restrict__ fb1, const float* __restrict__ fb2,
    const unsigned* __restrict__ wsW1, const short* __restrict__ wsW,
    float* __restrict__ xc, float* __restrict__ sums, unsigned* __restrict__ maxu)
{
    __shared__ unsigned shH[2][1584];            // packed halo dbuf 12672B
    __shared__ __align__(16) unsigned w1p[1008]; // conv1 W f16-pair  4032B
    __shared__ __align__(16) float  fbl[112];    // conv1 bias         448B
    __shared__ float  red[4 * 32 * 2];           // ta partials       1024B

    // ---- XCD-chunked swizzle (bijective: 4096 % 8 == 0) ----
    const int orig = blockIdx.x;
    const int wg   = (orig & 7) * 512 + (orig >> 3);
    const int b    = wg >> 9;
    const int h0   = ((wg >> 4) & 31) << 3;
    const int w0   = (wg & 15) << 4;

    const int tid = threadIdx.x;
    const int wv = tid >> 6, ln = tid & 63;
    const int col = ln & 15, lq = ln >> 4;

    // ---- weight staging: plain copies (packed by kInit) ----
    #pragma unroll
    for (int j = 0; j < 4; ++j) {
        int i = tid + j * 256;
        if (i < 1008) w1p[i] = wsW1[i];
    }
    if (tid < 112) fbl[tid] = fb1[tid];

    // ---- staging slots: ROW-major global walk, col-major LDS (stride 11) ----
    int  sOff[7], sLds[7];
    bool sOK[7];
    #pragma unroll
    for (int j = 0; j < 7; ++j) {
        const int i = tid + j * 256;
        int gl = i / 180, rem = i - gl * 180;
        int r = rem / 18, c = rem - r * 18;      // row-major walk (coalesced)
        int gh = h0 + r - 1, gw = w0 + c - 1;
        sOK[j]  = (i < 1440) && ((unsigned)gh < 256u) && ((unsigned)gw < 256u);
        sOff[j] = ((b * 28 + gl) << 16) + (gh << 8) + gw;
        sLds[j] = gl * 198 + c * 11 + r;         // col-major store, stride 11
    }

    // ---- prologue: load + publish chunk 0 into buffer 0 ----
    float2 pf[7];
    #pragma unroll
    for (int j = 0; j < 7; ++j) {
        pf[j] = make_float2(0.f, 0.f);
        if (sOK[j]) {
            size_t o = (size_t)sOff[j];
            pf[j].x = y[o];
            pf[j].y = mask[o];
        }
    }
    #pragma unroll
    for (int j = 0; j < 7; ++j) {
        if (tid + j * 256 < 1440)
            shH[0][sLds[j]] = pk16(pf[j].x, pf[j].y);
    }

    // ---- C accumulators, init with conv2 bias ----
    f32x4 acc[2][4];   // [pg][t]
    #pragma unroll
    for (int t = 0; t < 4; ++t) {
        #pragma unroll
        for (int r = 0; r < 4; ++r) {
            float bv = fb2[t * 16 + lq * 4 + r];
            acc[0][t][r] = bv;
            acc[1][t][r] = bv;
        }
    }
    __syncthreads();   // chunk-0 halo + weights visible

    // ---- K-chunk loop, double-buffered: 1 barrier per chunk ----
    #pragma unroll 1
    for (int s = 0; s < 4; ++s) {
        const int cur = s & 1;

        // issue next chunk's loads NOW (latency hides under compute below)
        const int TOTn = (s == 2) ? 720 : 1440;
        if (s < 3) {
            const int chAdd = ((s + 1) * 8) << 16;
            #pragma unroll
            for (int j = 0; j < 7; ++j) {
                pf[j] = make_float2(0.f, 0.f);
                if (sOK[j] && (tid + j * 256) < TOTn) {
                    size_t o = (size_t)(sOff[j] + chAdd);
                    pf[j].x = y[o];
                    pf[j].y = mask[o];
                }
            }
        }

        // A-fragments direct from global (L2-resident)
        s16x8 A[4];
        #pragma unroll
        for (int t = 0; t < 4; ++t)
            A[t] = *(const s16x8*)&wsW[(t * 16 + col) * 128 + s * 32 + lq * 8];

        // ---- conv1 -> B-fragments (f16 dot2, f32 accum) ----
        unsigned Bu[2][4] = {{0u,0u,0u,0u},{0u,0u,0u,0u}};

        if (s < 3 || lq < 2) {             // s=3, lq>=2 -> channels >=112
            #pragma unroll
            for (int gidx = 0; gidx < 2; ++gidx) {
                const int gl = 2 * lq + gidx;      // local group 0..7
                const int c4 = s * 8 + gl;         // global channel-quad
                const unsigned* hb = &shH[cur][gl * 198 + col * 11 + 2 * wv];
                unsigned hl[3][4];                 // [col][row] packed (y,m)
                #pragma unroll
                for (int cc = 0; cc < 3; ++cc)
                    #pragma unroll
                    for (int rr = 0; rr < 4; ++rr)
                        hl[cc][rr] = hb[cc * 11 + rr];

                const f32x4 bias4 = *(const f32x4*)&fbl[c4 * 4];
                float a[4][2];
                #pragma unroll
                for (int jj = 0; jj < 4; ++jj) {
                    a[jj][0] = bias4[jj];
                    a[jj][1] = bias4[jj];
                }
                const uint4* wq4 = (const uint4*)&w1p[c4 * 36];
                #pragma unroll
                for (int q = 0; q < 9; ++q) {
                    const uint4 w = wq4[q];        // 4 channels' (wy,wm) pairs
                    const int dy = q / 3, dx = q % 3;
                    const unsigned h0p = hl[dx][dy];
                    const unsigned h1p = hl[dx][dy + 1];
                    a[0][0] = dot2(h0p, w.x, a[0][0]);
                    a[0][1] = dot2(h1p, w.x, a[0][1]);
                    a[1][0] = dot2(h0p, w.y, a[1][0]);
                    a[1][1] = dot2(h1p, w.y, a[1][1]);
                    a[2][0] = dot2(h0p, w.z, a[2][0]);
                    a[2][1] = dot2(h1p, w.z, a[2][1]);
                    a[3][0] = dot2(h0p, w.w, a[3][0]);
                    a[3][1] = dot2(h1p, w.w, a[3][1]);
                }
                #pragma unroll
                for (int pg = 0; pg < 2; ++pg) {
                    const float r0 = fmaxf(a[0][pg], 0.f);
                    const float r1 = fmaxf(a[1][pg], 0.f);
                    const float r2 = fmaxf(a[2][pg], 0.f);
                    const float r3 = fmaxf(a[3][pg], 0.f);
                    unsigned wlo, whi;
                    asm("v_cvt_pk_bf16_f32 %0, %1, %2" : "=v"(wlo) : "v"(r0), "v"(r1));
                    asm("v_cvt_pk_bf16_f32 %0, %1, %2" : "=v"(whi) : "v"(r2), "v"(r3));
                    Bu[pg][gidx * 2 + 0] = wlo;
                    Bu[pg][gidx * 2 + 1] = whi;
                }
            }
        }

        s16x8 Bf[2];
        #pragma unroll
        for (int pg = 0; pg < 2; ++pg) {
            union { unsigned u[4]; s16x8 v; } cvt;
            cvt.u[0] = Bu[pg][0]; cvt.u[1] = Bu[pg][1];
            cvt.u[2] = Bu[pg][2]; cvt.u[3] = Bu[pg][3];
            Bf[pg] = cvt.v;
        }

        #pragma unroll
        for (int pg = 0; pg < 2; ++pg)
            #pragma unroll
            for (int t = 0; t < 4; ++t)
                acc[pg][t] = __builtin_amdgcn_mfma_f32_16x16x32_bf16(
                                 A[t], Bf[pg], acc[pg][t], 0, 0, 0);

        // ---- publish prefetched chunk into the OTHER buffer ----
        if (s < 3) {
            #pragma unroll
            for (int j = 0; j < 7; ++j) {
                if (tid + j * 256 < TOTn)
                    shH[cur ^ 1][sLds[j]] = pk16(pf[j].x, pf[j].y);
            }
            __syncthreads();   // next-chunk halo visible to all waves
        }
    }

    // ---- epilogue (proven rounds 3-17) ----
    float* xc0 = xc + (((size_t)b * 2) << 16);
    float* xc1 = xc0 + 65536;

    float run_s[2][4], run_m[2][4];
    #pragma unroll
    for (int t = 0; t < 2; ++t)
        #pragma unroll
        for (int r = 0; r < 4; ++r) { run_s[t][r] = 0.f; run_m[t][r] = -3.4e38f; }

    #pragma unroll
    for (int pg = 0; pg < 2; ++pg) {
        float m8 = -3.4e38f, s8 = 0.f;
        #pragma unroll
        for (int t = 2; t < 4; ++t)
            #pragma unroll
            for (int r = 0; r < 4; ++r) {
                float v = acc[pg][t][r];
                m8 = fmaxf(m8, v); s8 += v;
            }
        m8 = fmaxf(m8, __shfl_xor(m8, 16));
        m8 = fmaxf(m8, __shfl_xor(m8, 32));
        s8 += __shfl_xor(s8, 16);
        s8 += __shfl_xor(s8, 32);
        if (ln < 16) {
            int row = h0 + 2 * wv + pg;
            xc0[(row << 8) + w0 + ln] = m8;
            xc1[(row << 8) + w0 + ln] = s8 * (1.f / 32.f);
        }
        #pragma unroll
        for (int t = 0; t < 2; ++t)
            #pragma unroll
            for (int r = 0; r < 4; ++r) {
                float v = acc[pg][t][r];
                run_s[t][r] += v;
                run_m[t][r] = fmaxf(run_m[t][r], v);
            }
    }

    #pragma unroll
    for (int t = 0; t < 2; ++t)
        #pragma unroll
        for (int r = 0; r < 4; ++r) {
            float s = run_s[t][r], m = run_m[t][r];
            #pragma unroll
            for (int off = 1; off < 16; off <<= 1) {
                s += __shfl_xor(s, off);
                m = fmaxf(m, __shfl_xor(m, off));
            }
            if (col == 0) {
                int ch = t * 16 + lq * 4 + r;
                red[(wv * 32 + ch) * 2 + 0] = s;
                red[(wv * 32 + ch) * 2 + 1] = m;
            }
        }
    __syncthreads();
    if (tid < 32) {
        float s = red[tid*2] + red[(32+tid)*2] + red[(64+tid)*2] + red[(96+tid)*2];
        float m = fmaxf(fmaxf(red[tid*2+1], red[(32+tid)*2+1]),
                        fmaxf(red[(64+tid)*2+1], red[(96+tid)*2+1]));
        atomicAdd(&sums[b*32 + tid], s);
        unsigned ub  = __float_as_uint(m);
        unsigned key = (ub & 0x80000000u) ? ~ub : (ub | 0x80000000u);
        atomicMax(&maxu[b*32 + tid], key);
    }
}

// ---------------------------------------------------------------------------
// Kernel B: finish ta mean/max, run pgm MLP on both, alpha = sum.
// ---------------------------------------------------------------------------
__global__ __launch_bounds__(256) void kB(
    const float* __restrict__ sums, const unsigned* __restrict__ maxu,
    const float* __restrict__ aw1, const float* __restrict__ ab1,
    const float* __restrict__ aw2, const float* __restrict__ ab2,
    const float* __restrict__ aw3, const float* __restrict__ ab3,
    float* __restrict__ out)
{
    __shared__ float xa[8][32], xm[8][32], h1a[8][32], h1m[8][32];
    const int tid = threadIdx.x;
    const int b = tid >> 5, i = tid & 31;

    xa[b][i] = sums[b*32 + i] * (1.f/65536.f);
    unsigned u = maxu[b*32 + i];
    unsigned bits = (u & 0x80000000u) ? (u ^ 0x80000000u) : ~u;
    xm[b][i] = __uint_as_float(bits);
    __syncthreads();

    float sa = ab1[i], sm = ab1[i];
    #pragma unroll
    for (int j = 0; j < 32; ++j) {
        float w = aw1[i*32 + j];
        sa += w * xa[b][j]; sm += w * xm[b][j];
    }
    __syncthreads();
    h1a[b][i] = leaky(sa); h1m[b][i] = leaky(sm);
    __syncthreads();

    sa = ab2[i]; sm = ab2[i];
    #pragma unroll
    for (int j = 0; j < 32; ++j) {
        float w = aw2[i*32 + j];
        sa += w * h1a[b][j]; sm += w * h1m[b][j];
    }
    float h2a = leaky(sa), h2m = leaky(sm);

    float pa = aw3[i] * h2a, pm = aw3[i] * h2m;
    #pragma unroll
    for (int off = 16; off > 0; off >>= 1) {
        pa += __shfl_xor(pa, off);
        pm += __shfl_xor(pm, off);
    }
    if (i == 0) {
        float za = fmaxf(pa + ab3[0], 0.f) + 1e-6f;
        float zm = fmaxf(pm + ab3[0], 0.f) + 1e-6f;
        out[b] = za + zm;
    }
}

// ---------------------------------------------------------------------------
// kC: fused beta chain; phase 3 MFMA (R15-proven). XCD-chunked swizzle
// matching kA's batch->XCD mapping.
// ---------------------------------------------------------------------------
__global__ __launch_bounds__(256, 3) void kC(
    const float* __restrict__ xc,
    const float* __restrict__ wT1g, const float* __restrict__ bb1,
    const short* __restrict__ wsW2b, const float* __restrict__ bb2,
    const float* __restrict__ bw3, const float* __restrict__ bb3,
    float* __restrict__ betaout)
{
    __shared__ float shX[2 * 484];     // xc halo [2][22][22]    3872B
    __shared__ float shB1[16 * 400];   // b1 [o][20][20]        25600B
    __shared__ float shB2[16 * 324];   // b2 [o][18][18]        20736B

    // ---- XCD-chunked swizzle (bijective: 2048 % 8 == 0) ----
    const int orig = blockIdx.x;
    const int wg   = (orig & 7) * 256 + (orig >> 3);
    const int b    = wg >> 8;
    const int h0   = ((wg >> 4) & 15) << 4;
    const int w0   = (wg & 15) << 4;
    const int tid = threadIdx.x;
    const int ln  = tid & 63, wv = tid >> 6;
    const int col = ln & 15,  lq = ln >> 4;

    for (int i = tid; i < 968; i += 256) {
        int ch = i / 484, rem = i - ch * 484;
        int r = rem / 22, c = rem - r * 22;
        int gh = h0 + r - 3, gw = w0 + c - 3;
        float v = 0.f;
        if ((unsigned)gh < 256u && (unsigned)gw < 256u)
            v = xc[(((size_t)b * 2 + ch) << 16) + (gh << 8) + gw];
        shX[i] = v;
    }
    __syncthreads();

    // ---- phase 2: b1 = leaky(conv3x3(xc)) on 20x20 (VALU, proven) ----
    const f32x4 bias1_0 = *(const f32x4*)&bb1[0];
    const f32x4 bias1_1 = *(const f32x4*)&bb1[4];
    const f32x4 bias1_2 = *(const f32x4*)&bb1[8];
    const f32x4 bias1_3 = *(const f32x4*)&bb1[12];
    #pragma unroll 1
    for (int p = tid; p < 400; p += 256) {
        int r1 = p / 20, c1 = p - r1 * 20;
        f32x4 a0 = bias1_0, a1 = bias1_1, a2 = bias1_2, a3 = bias1_3;
        #pragma unroll
        for (int ic = 0; ic < 2; ++ic)
            #pragma unroll
            for (int k = 0; k < 9; ++k) {
                float v = shX[ic * 484 + (r1 + k / 3) * 22 + (c1 + k % 3)];
                const f32x4* wp = (const f32x4*)&wT1g[(ic * 9 + k) << 4];
                a0 += wp[0] * v; a1 += wp[1] * v;
                a2 += wp[2] * v; a3 += wp[3] * v;
            }
        int gh = h0 - 2 + r1, gw = w0 - 2 + c1;
        if (((unsigned)gh < 256u) && ((unsigned)gw < 256u)) {
            shB1[ 0*400+p]=leaky(a0[0]); shB1[ 1*400+p]=leaky(a0[1]);
            shB1[ 2*400+p]=leaky(a0[2]); shB1[ 3*400+p]=leaky(a0[3]);
            shB1[ 4*400+p]=leaky(a1[0]); shB1[ 5*400+p]=leaky(a1[1]);
            shB1[ 6*400+p]=leaky(a1[2]); shB1[ 7*400+p]=leaky(a1[3]);
            shB1[ 8*400+p]=leaky(a2[0]); shB1[ 9*400+p]=leaky(a2[1]);
            shB1[10*400+p]=leaky(a2[2]); shB1[11*400+p]=leaky(a2[3]);
            shB1[12*400+p]=leaky(a3[0]); shB1[13*400+p]=leaky(a3[1]);
            shB1[14*400+p]=leaky(a3[2]); shB1[15*400+p]=leaky(a3[3]);
        } else {
            #pragma unroll
            for (int o = 0; o < 16; ++o) shB1[o*400+p] = 0.f;
        }
    }
    __syncthreads();

    // ---- phase 3 (MFMA): b2 = leaky(conv3x3(b1)), 16->16, K'=160 ----
    {
        s16x8 A3[5];
        #pragma unroll
        for (int s = 0; s < 5; ++s)
            A3[s] = *(const s16x8*)&wsW2b[col * 160 + s * 32 + lq * 8];
        f32x4 bias3;
        #pragma unroll
        for (int r = 0; r < 4; ++r) bias3[r] = bb2[lq * 4 + r];

        #pragma unroll 1
        for (int g = wv; g < 21; g += 4) {
            const int p  = g * 16 + col;
            const int pc = (p < 324) ? p : 0;
            const int r2 = (pc * 3641) >> 16;      // /18
            const int c2 = pc - r2 * 18;
            const int pbase = r2 * 20 + c2;
            f32x4 c3 = bias3;
            #pragma unroll
            for (int s = 0; s < 5; ++s) {
                const int q = 2 * s + (lq >> 1);
                s16x8 B3;
                if (s == 4 && lq >= 2) {
                    #pragma unroll
                    for (int j = 0; j < 8; ++j) B3[j] = 0;
                } else {
                    const int dy = (q * 11) >> 5;  // q/3 for q<9
                    const int dx = q - 3 * dy;
                    const float* src = &shB1[((lq & 1) * 8) * 400
                                             + pbase + dy * 20 + dx];
                    float f0 = src[0],    f1 = src[400],  f2 = src[800];
                    float f3 = src[1200], f4 = src[1600], f5 = src[2000];
                    float f6 = src[2400], f7 = src[2800];
                    unsigned u0, u1, u2, u3;
                    asm("v_cvt_pk_bf16_f32 %0, %1, %2" : "=v"(u0) : "v"(f0), "v"(f1));
                    asm("v_cvt_pk_bf16_f32 %0, %1, %2" : "=v"(u1) : "v"(f2), "v"(f3));
                    asm("v_cvt_pk_bf16_f32 %0, %1, %2" : "=v"(u2) : "v"(f4), "v"(f5));
                    asm("v_cvt_pk_bf16_f32 %0, %1, %2" : "=v"(u3) : "v"(f6), "v"(f7));
                    union { unsigned u[4]; s16x8 v; } cv;
                    cv.u[0] = u0; cv.u[1] = u1; cv.u[2] = u2; cv.u[3] = u3;
                    B3 = cv.v;
                }
                c3 = __builtin_amdgcn_mfma_f32_16x16x32_bf16(A3[s], B3, c3, 0, 0, 0);
            }
            if (p < 324) {
                const int gh = h0 - 1 + r2, gw = w0 - 1 + c2;
                const bool vimg = ((unsigned)gh < 256u) && ((unsigned)gw < 256u);
                #pragma unroll
                for (int r = 0; r < 4; ++r)
                    shB2[(lq * 4 + r) * 324 + p] = vimg ? leaky(c3[r]) : 0.f;
            }
        }
    }
    __syncthreads();

    // ---- phase 4: beta = sigmoid(conv3x3(b2)) on the 16x16 tile ----
    {
        int r3 = tid >> 4, c3 = tid & 15;
        float a = bb3[0];
        #pragma unroll 4
        for (int ic = 0; ic < 16; ++ic)
            #pragma unroll
            for (int k = 0; k < 9; ++k)
                a += bw3[ic * 9 + k]
                     * shB2[ic * 324 + (r3 + k / 3) * 18 + (c3 + k % 3)];
        betaout[((size_t)b << 16) + ((h0 + r3) << 8) + (w0 + c3)]
            = 1.f / (1.f + expf(-a));
    }
}

// ---------------------------------------------------------------------------
extern "C" void kernel_launch(void* const* d_in, const int* in_sizes, int n_in,
                              void* d_out, int out_size, void* d_ws, size_t ws_size,
                              hipStream_t stream) {
    const float* y    = (const float*)d_in[0];
    const float* mask = (const float*)d_in[1];
    const float* fw1  = (const float*)d_in[2];
    const float* fb1  = (const float*)d_in[3];
    const float* fw2  = (const float*)d_in[4];
    const float* fb2  = (const float*)d_in[5];
    const float* aw1  = (const float*)d_in[6];
    const float* ab1  = (const float*)d_in[7];
    const float* aw2  = (const float*)d_in[8];
    const float* ab2  = (const float*)d_in[9];
    const float* aw3  = (const float*)d_in[10];
    const float* ab3  = (const float*)d_in[11];
    const float* bw1  = (const float*)d_in[12];
    const float* bb1  = (const float*)d_in[13];
    const float* bw2  = (const float*)d_in[14];
    const float* bb2  = (const float*)d_in[15];
    const float* bw3  = (const float*)d_in[16];
    const float* bb3  = (const float*)d_in[17];
    float* out = (float*)d_out;

    char* ws = (char*)d_ws;
    float*    sums  = (float*)ws;                // 1 KB
    unsigned* maxu  = (unsigned*)(ws + 1024);    // 1 KB
    float*    wT1g  = (float*)(ws + 2048);       // 1152 B
    short*    wsW2b = (short*)(ws + 3200);       // 5120 B (ends 8320)
    unsigned* wsW1  = (unsigned*)(ws + 12416);   // 4032 B (ends 16448)
    short*    wsW   = (short*)(ws + 20480);      // 16384 B (ends 36864)
    float*    xc    = (float*)(ws + 65536);      // 4 MB

    kInit<<<1, 256, 0, stream>>>(sums, maxu, bw1, bw2, fw1, fw2,
                                 wT1g, wsW2b, wsW1, wsW);
    kA<<<4096, 256, 0, stream>>>(y, mask, fb1, fb2, wsW1, wsW,
                                 xc, sums, maxu);
    kB<<<1, 256, 0, stream>>>(sums, maxu, aw1, ab1, aw2, ab2, aw3, ab3, out);
    kC<<<2048, 256, 0, stream>>>(xc, wT1g, bb1, wsW2b, bb2, bw3, bb3,
                                 out + 8);
}

// Round 20
// 117.985 us; speedup vs baseline: 1.6038x; 1.0259x over previous
//
#include <hip/hip_runtime.h>
#include <hip/hip_bf16.h>
#include <math.h>

// ---------------------------------------------------------------------------
// HyperParamNet — round 20.
// R19 reproduced the best config (121us; kA 92us). Last clean lever:
// kA halo bank conflicts (3.74M). With group stride 198, per-instruction
// bank = (12*lq + 11*col) mod 32 -> 4-way conflicts (e.g. bank 4 gets
// lq0/c12, lq1/c8, lq2/c4, lq3/c0). Stride 200 => 2S=16 mod 32 ->
// lq offsets {0,16,0,16}; col-residue set V and V+16 are complements
// mod 32 -> exactly 2 lanes/bank = free (m136). LDS +128B only.
// Single change: stride 198->200 (shH size, sLds, hb base). Rest identical.
// ---------------------------------------------------------------------------

using s16x8 = __attribute__((ext_vector_type(8))) short;
using f32x4 = __attribute__((ext_vector_type(4))) float;
using f32x2 = __attribute__((ext_vector_type(2))) float;

__device__ __forceinline__ float leaky(float x) {
    return x >= 0.f ? x : 0.01f * x;
}

__device__ __forceinline__ unsigned short f2bf(float f) {
    unsigned x = __float_as_uint(f);
    return (unsigned short)((x + 0x7FFFu + ((x >> 16) & 1u)) >> 16);
}

__device__ __forceinline__ unsigned pk16(float a, float b) {
    unsigned r;
    asm("v_cvt_pkrtz_f16_f32 %0, %1, %2" : "=v"(r) : "v"(a), "v"(b));
    return r;
}

__device__ __forceinline__ float dot2(unsigned a, unsigned b, float c) {
    float r;
    asm("v_dot2_f32_f16 %0, %1, %2, %3" : "=v"(r) : "v"(a), "v"(b), "v"(c));
    return r;
}

// ---------------------------------------------------------------------------
// kInit: zero ta accumulators; transpose bw1 (kC ph2); pack bw2 bf16 q-major
// (kC ph3 MFMA); pack conv1 W as f16-pair dwords + conv2 W bf16 (kA).
// ---------------------------------------------------------------------------
__global__ void kInit(float* __restrict__ sums, unsigned* __restrict__ maxu,
                      const float* __restrict__ bw1, const float* __restrict__ bw2,
                      const float* __restrict__ fw1, const float* __restrict__ fw2,
                      float* __restrict__ wT1g, short* __restrict__ wsW2b,
                      unsigned* __restrict__ wsW1, short* __restrict__ wsW) {
    int t = threadIdx.x;   // 256
    sums[t] = 0.f;
    maxu[t] = 0u;
    for (int i = t; i < 288; i += 256) {      // wT1g[(ic*9+k)*16 + o]
        int o = i & 15, rest = i >> 4;
        int ic = rest / 9, k = rest - ic * 9;
        wT1g[i] = bw1[(o * 2 + ic) * 9 + k];
    }
    // bw2 bf16, q-major K-pad: wsW2b[o*160 + q*16 + ic], q<9 valid
    for (int i = t; i < 2560; i += 256) {
        int o = i / 160, kp = i - o * 160;
        int q = kp >> 4, ic = kp & 15;
        wsW2b[i] = (q < 9) ? (short)f2bf(bw2[(o * 16 + ic) * 9 + q]) : (short)0;
    }
    // conv1 weights: wsW1[(c4*9+q)*4 + cl] = f16-pair (wy, wm), ch=4*c4+cl
    for (int i = t; i < 1008; i += 256) {
        int c4 = i / 36, rem = i - c4 * 36;
        int q = rem >> 2, cl = rem & 3;
        int ch = c4 * 4 + cl;
        wsW1[i] = pk16(fw1[ch * 18 + q], fw1[ch * 18 + 9 + q]);
    }
    // conv2 weights: bf16 [64][128], K zero-padded 112..127
    for (int i = t; i < 8192; i += 256) {
        int o = i >> 7, k = i & 127;
        wsW[i] = (k < 112) ? (short)f2bf(fw2[o * 112 + k]) : (short)0;
    }
}

// ---------------------------------------------------------------------------
// kA: fused conv1(grouped 3x3, f16 dot2) + conv2(1x1, MFMA) + xc + ta reduce.
// Flat grid 4096, XCD-chunked swizzle (XCD k owns batch k). Block 256 =
// 4 waves; wave wv owns rows 2wv..2wv+1, lane (col,lq): pixel col, k-slice lq.
// Halo LDS: ONE dword/pixel = packed f16(y,m); col-major stride 11,
// GROUP STRIDE 200 (bank-conflict-free: 2 lanes/bank), dbuf.
// lb(256,4): R8/R13/R18 all prove >4 waves/SIMD spills this kernel.
// ---------------------------------------------------------------------------
__global__ __launch_bounds__(256, 4) void kA(
    const float* __restrict__ y, const float* __restrict__ mask,
    const float* __restrict__ fb1, const float* __restrict__ fb2,
    const unsigned* __restrict__ wsW1, const short* __restrict__ wsW,
    float* __restrict__ xc, float* __restrict__ sums, unsigned* __restrict__ maxu)
{
    __shared__ unsigned shH[2][1600];            // packed halo dbuf 12800B
    __shared__ __align__(16) unsigned w1p[1008]; // conv1 W f16-pair  4032B
    __shared__ __align__(16) float  fbl[112];    // conv1 bias         448B
    __shared__ float  red[4 * 32 * 2];           // ta partials       1024B

    // ---- XCD-chunked swizzle (bijective: 4096 % 8 == 0) ----
    const int orig = blockIdx.x;
    const int wg   = (orig & 7) * 512 + (orig >> 3);
    const int b    = wg >> 9;
    const int h0   = ((wg >> 4) & 31) << 3;
    const int w0   = (wg & 15) << 4;

    const int tid = threadIdx.x;
    const int wv = tid >> 6, ln = tid & 63;
    const int col = ln & 15, lq = ln >> 4;

    // ---- weight staging: plain copies (packed by kInit) ----
    #pragma unroll
    for (int j = 0; j < 4; ++j) {
        int i = tid + j * 256;
        if (i < 1008) w1p[i] = wsW1[i];
    }
    if (tid < 112) fbl[tid] = fb1[tid];

    // ---- staging slots: ROW-major global walk, col-major LDS (stride 11,
    //      group stride 200) ----
    int  sOff[7], sLds[7];
    bool sOK[7];
    #pragma unroll
    for (int j = 0; j < 7; ++j) {
        const int i = tid + j * 256;
        int gl = i / 180, rem = i - gl * 180;
        int r = rem / 18, c = rem - r * 18;      // row-major walk (coalesced)
        int gh = h0 + r - 1, gw = w0 + c - 1;
        sOK[j]  = (i < 1440) && ((unsigned)gh < 256u) && ((unsigned)gw < 256u);
        sOff[j] = ((b * 28 + gl) << 16) + (gh << 8) + gw;
        sLds[j] = gl * 200 + c * 11 + r;         // group stride 200
    }

    // ---- prologue: load + publish chunk 0 into buffer 0 ----
    float2 pf[7];
    #pragma unroll
    for (int j = 0; j < 7; ++j) {
        pf[j] = make_float2(0.f, 0.f);
        if (sOK[j]) {
            size_t o = (size_t)sOff[j];
            pf[j].x = y[o];
            pf[j].y = mask[o];
        }
    }
    #pragma unroll
    for (int j = 0; j < 7; ++j) {
        if (tid + j * 256 < 1440)
            shH[0][sLds[j]] = pk16(pf[j].x, pf[j].y);
    }

    // ---- C accumulators, init with conv2 bias ----
    f32x4 acc[2][4];   // [pg][t]
    #pragma unroll
    for (int t = 0; t < 4; ++t) {
        #pragma unroll
        for (int r = 0; r < 4; ++r) {
            float bv = fb2[t * 16 + lq * 4 + r];
            acc[0][t][r] = bv;
            acc[1][t][r] = bv;
        }
    }
    __syncthreads();   // chunk-0 halo + weights visible

    // ---- K-chunk loop, double-buffered: 1 barrier per chunk ----
    #pragma unroll 1
    for (int s = 0; s < 4; ++s) {
        const int cur = s & 1;

        // issue next chunk's loads NOW (latency hides under compute below)
        const int TOTn = (s == 2) ? 720 : 1440;
        if (s < 3) {
            const int chAdd = ((s + 1) * 8) << 16;
            #pragma unroll
            for (int j = 0; j < 7; ++j) {
                pf[j] = make_float2(0.f, 0.f);
                if (sOK[j] && (tid + j * 256) < TOTn) {
                    size_t o = (size_t)(sOff[j] + chAdd);
                    pf[j].x = y[o];
                    pf[j].y = mask[o];
                }
            }
        }

        // A-fragments direct from global (L2-resident)
        s16x8 A[4];
        #pragma unroll
        for (int t = 0; t < 4; ++t)
            A[t] = *(const s16x8*)&wsW[(t * 16 + col) * 128 + s * 32 + lq * 8];

        // ---- conv1 -> B-fragments (f16 dot2, f32 accum) ----
        unsigned Bu[2][4] = {{0u,0u,0u,0u},{0u,0u,0u,0u}};

        if (s < 3 || lq < 2) {             // s=3, lq>=2 -> channels >=112
            #pragma unroll
            for (int gidx = 0; gidx < 2; ++gidx) {
                const int gl = 2 * lq + gidx;      // local group 0..7
                const int c4 = s * 8 + gl;         // global channel-quad
                const unsigned* hb = &shH[cur][gl * 200 + col * 11 + 2 * wv];
                unsigned hl[3][4];                 // [col][row] packed (y,m)
                #pragma unroll
                for (int cc = 0; cc < 3; ++cc)
                    #pragma unroll
                    for (int rr = 0; rr < 4; ++rr)
                        hl[cc][rr] = hb[cc * 11 + rr];

                const f32x4 bias4 = *(const f32x4*)&fbl[c4 * 4];
                float a[4][2];
                #pragma unroll
                for (int jj = 0; jj < 4; ++jj) {
                    a[jj][0] = bias4[jj];
                    a[jj][1] = bias4[jj];
                }
                const uint4* wq4 = (const uint4*)&w1p[c4 * 36];
                #pragma unroll
                for (int q = 0; q < 9; ++q) {
                    const uint4 w = wq4[q];        // 4 channels' (wy,wm) pairs
                    const int dy = q / 3, dx = q % 3;
                    const unsigned h0p = hl[dx][dy];
                    const unsigned h1p = hl[dx][dy + 1];
                    a[0][0] = dot2(h0p, w.x, a[0][0]);
                    a[0][1] = dot2(h1p, w.x, a[0][1]);
                    a[1][0] = dot2(h0p, w.y, a[1][0]);
                    a[1][1] = dot2(h1p, w.y, a[1][1]);
                    a[2][0] = dot2(h0p, w.z, a[2][0]);
                    a[2][1] = dot2(h1p, w.z, a[2][1]);
                    a[3][0] = dot2(h0p, w.w, a[3][0]);
                    a[3][1] = dot2(h1p, w.w, a[3][1]);
                }
                #pragma unroll
                for (int pg = 0; pg < 2; ++pg) {
                    const float r0 = fmaxf(a[0][pg], 0.f);
                    const float r1 = fmaxf(a[1][pg], 0.f);
                    const float r2 = fmaxf(a[2][pg], 0.f);
                    const float r3 = fmaxf(a[3][pg], 0.f);
                    unsigned wlo, whi;
                    asm("v_cvt_pk_bf16_f32 %0, %1, %2" : "=v"(wlo) : "v"(r0), "v"(r1));
                    asm("v_cvt_pk_bf16_f32 %0, %1, %2" : "=v"(whi) : "v"(r2), "v"(r3));
                    Bu[pg][gidx * 2 + 0] = wlo;
                    Bu[pg][gidx * 2 + 1] = whi;
                }
            }
        }

        s16x8 Bf[2];
        #pragma unroll
        for (int pg = 0; pg < 2; ++pg) {
            union { unsigned u[4]; s16x8 v; } cvt;
            cvt.u[0] = Bu[pg][0]; cvt.u[1] = Bu[pg][1];
            cvt.u[2] = Bu[pg][2]; cvt.u[3] = Bu[pg][3];
            Bf[pg] = cvt.v;
        }

        #pragma unroll
        for (int pg = 0; pg < 2; ++pg)
            #pragma unroll
            for (int t = 0; t < 4; ++t)
                acc[pg][t] = __builtin_amdgcn_mfma_f32_16x16x32_bf16(
                                 A[t], Bf[pg], acc[pg][t], 0, 0, 0);

        // ---- publish prefetched chunk into the OTHER buffer ----
        if (s < 3) {
            #pragma unroll
            for (int j = 0; j < 7; ++j) {
                if (tid + j * 256 < TOTn)
                    shH[cur ^ 1][sLds[j]] = pk16(pf[j].x, pf[j].y);
            }
            __syncthreads();   // next-chunk halo visible to all waves
        }
    }

    // ---- epilogue (proven rounds 3-19) ----
    float* xc0 = xc + (((size_t)b * 2) << 16);
    float* xc1 = xc0 + 65536;

    float run_s[2][4], run_m[2][4];
    #pragma unroll
    for (int t = 0; t < 2; ++t)
        #pragma unroll
        for (int r = 0; r < 4; ++r) { run_s[t][r] = 0.f; run_m[t][r] = -3.4e38f; }

    #pragma unroll
    for (int pg = 0; pg < 2; ++pg) {
        float m8 = -3.4e38f, s8 = 0.f;
        #pragma unroll
        for (int t = 2; t < 4; ++t)
            #pragma unroll
            for (int r = 0; r < 4; ++r) {
                float v = acc[pg][t][r];
                m8 = fmaxf(m8, v); s8 += v;
            }
        m8 = fmaxf(m8, __shfl_xor(m8, 16));
        m8 = fmaxf(m8, __shfl_xor(m8, 32));
        s8 += __shfl_xor(s8, 16);
        s8 += __shfl_xor(s8, 32);
        if (ln < 16) {
            int row = h0 + 2 * wv + pg;
            xc0[(row << 8) + w0 + ln] = m8;
            xc1[(row << 8) + w0 + ln] = s8 * (1.f / 32.f);
        }
        #pragma unroll
        for (int t = 0; t < 2; ++t)
            #pragma unroll
            for (int r = 0; r < 4; ++r) {
                float v = acc[pg][t][r];
                run_s[t][r] += v;
                run_m[t][r] = fmaxf(run_m[t][r], v);
            }
    }

    #pragma unroll
    for (int t = 0; t < 2; ++t)
        #pragma unroll
        for (int r = 0; r < 4; ++r) {
            float s = run_s[t][r], m = run_m[t][r];
            #pragma unroll
            for (int off = 1; off < 16; off <<= 1) {
                s += __shfl_xor(s, off);
                m = fmaxf(m, __shfl_xor(m, off));
            }
            if (col == 0) {
                int ch = t * 16 + lq * 4 + r;
                red[(wv * 32 + ch) * 2 + 0] = s;
                red[(wv * 32 + ch) * 2 + 1] = m;
            }
        }
    __syncthreads();
    if (tid < 32) {
        float s = red[tid*2] + red[(32+tid)*2] + red[(64+tid)*2] + red[(96+tid)*2];
        float m = fmaxf(fmaxf(red[tid*2+1], red[(32+tid)*2+1]),
                        fmaxf(red[(64+tid)*2+1], red[(96+tid)*2+1]));
        atomicAdd(&sums[b*32 + tid], s);
        unsigned ub  = __float_as_uint(m);
        unsigned key = (ub & 0x80000000u) ? ~ub : (ub | 0x80000000u);
        atomicMax(&maxu[b*32 + tid], key);
    }
}

// ---------------------------------------------------------------------------
// Kernel B: finish ta mean/max, run pgm MLP on both, alpha = sum.
// ---------------------------------------------------------------------------
__global__ __launch_bounds__(256) void kB(
    const float* __restrict__ sums, const unsigned* __restrict__ maxu,
    const float* __restrict__ aw1, const float* __restrict__ ab1,
    const float* __restrict__ aw2, const float* __restrict__ ab2,
    const float* __restrict__ aw3, const float* __restrict__ ab3,
    float* __restrict__ out)
{
    __shared__ float xa[8][32], xm[8][32], h1a[8][32], h1m[8][32];
    const int tid = threadIdx.x;
    const int b = tid >> 5, i = tid & 31;

    xa[b][i] = sums[b*32 + i] * (1.f/65536.f);
    unsigned u = maxu[b*32 + i];
    unsigned bits = (u & 0x80000000u) ? (u ^ 0x80000000u) : ~u;
    xm[b][i] = __uint_as_float(bits);
    __syncthreads();

    float sa = ab1[i], sm = ab1[i];
    #pragma unroll
    for (int j = 0; j < 32; ++j) {
        float w = aw1[i*32 + j];
        sa += w * xa[b][j]; sm += w * xm[b][j];
    }
    __syncthreads();
    h1a[b][i] = leaky(sa); h1m[b][i] = leaky(sm);
    __syncthreads();

    sa = ab2[i]; sm = ab2[i];
    #pragma unroll
    for (int j = 0; j < 32; ++j) {
        float w = aw2[i*32 + j];
        sa += w * h1a[b][j]; sm += w * h1m[b][j];
    }
    float h2a = leaky(sa), h2m = leaky(sm);

    float pa = aw3[i] * h2a, pm = aw3[i] * h2m;
    #pragma unroll
    for (int off = 16; off > 0; off >>= 1) {
        pa += __shfl_xor(pa, off);
        pm += __shfl_xor(pm, off);
    }
    if (i == 0) {
        float za = fmaxf(pa + ab3[0], 0.f) + 1e-6f;
        float zm = fmaxf(pm + ab3[0], 0.f) + 1e-6f;
        out[b] = za + zm;
    }
}

// ---------------------------------------------------------------------------
// kC: fused beta chain; phase 3 MFMA (R15-proven). XCD-chunked swizzle
// matching kA's batch->XCD mapping.
// ---------------------------------------------------------------------------
__global__ __launch_bounds__(256, 3) void kC(
    const float* __restrict__ xc,
    const float* __restrict__ wT1g, const float* __restrict__ bb1,
    const short* __restrict__ wsW2b, const float* __restrict__ bb2,
    const float* __restrict__ bw3, const float* __restrict__ bb3,
    float* __restrict__ betaout)
{
    __shared__ float shX[2 * 484];     // xc halo [2][22][22]    3872B
    __shared__ float shB1[16 * 400];   // b1 [o][20][20]        25600B
    __shared__ float shB2[16 * 324];   // b2 [o][18][18]        20736B

    // ---- XCD-chunked swizzle (bijective: 2048 % 8 == 0) ----
    const int orig = blockIdx.x;
    const int wg   = (orig & 7) * 256 + (orig >> 3);
    const int b    = wg >> 8;
    const int h0   = ((wg >> 4) & 15) << 4;
    const int w0   = (wg & 15) << 4;
    const int tid = threadIdx.x;
    const int ln  = tid & 63, wv = tid >> 6;
    const int col = ln & 15,  lq = ln >> 4;

    for (int i = tid; i < 968; i += 256) {
        int ch = i / 484, rem = i - ch * 484;
        int r = rem / 22, c = rem - r * 22;
        int gh = h0 + r - 3, gw = w0 + c - 3;
        float v = 0.f;
        if ((unsigned)gh < 256u && (unsigned)gw < 256u)
            v = xc[(((size_t)b * 2 + ch) << 16) + (gh << 8) + gw];
        shX[i] = v;
    }
    __syncthreads();

    // ---- phase 2: b1 = leaky(conv3x3(xc)) on 20x20 (VALU, proven) ----
    const f32x4 bias1_0 = *(const f32x4*)&bb1[0];
    const f32x4 bias1_1 = *(const f32x4*)&bb1[4];
    const f32x4 bias1_2 = *(const f32x4*)&bb1[8];
    const f32x4 bias1_3 = *(const f32x4*)&bb1[12];
    #pragma unroll 1
    for (int p = tid; p < 400; p += 256) {
        int r1 = p / 20, c1 = p - r1 * 20;
        f32x4 a0 = bias1_0, a1 = bias1_1, a2 = bias1_2, a3 = bias1_3;
        #pragma unroll
        for (int ic = 0; ic < 2; ++ic)
            #pragma unroll
            for (int k = 0; k < 9; ++k) {
                float v = shX[ic * 484 + (r1 + k / 3) * 22 + (c1 + k % 3)];
                const f32x4* wp = (const f32x4*)&wT1g[(ic * 9 + k) << 4];
                a0 += wp[0] * v; a1 += wp[1] * v;
                a2 += wp[2] * v; a3 += wp[3] * v;
            }
        int gh = h0 - 2 + r1, gw = w0 - 2 + c1;
        if (((unsigned)gh < 256u) && ((unsigned)gw < 256u)) {
            shB1[ 0*400+p]=leaky(a0[0]); shB1[ 1*400+p]=leaky(a0[1]);
            shB1[ 2*400+p]=leaky(a0[2]); shB1[ 3*400+p]=leaky(a0[3]);
            shB1[ 4*400+p]=leaky(a1[0]); shB1[ 5*400+p]=leaky(a1[1]);
            shB1[ 6*400+p]=leaky(a1[2]); shB1[ 7*400+p]=leaky(a1[3]);
            shB1[ 8*400+p]=leaky(a2[0]); shB1[ 9*400+p]=leaky(a2[1]);
            shB1[10*400+p]=leaky(a2[2]); shB1[11*400+p]=leaky(a2[3]);
            shB1[12*400+p]=leaky(a3[0]); shB1[13*400+p]=leaky(a3[1]);
            shB1[14*400+p]=leaky(a3[2]); shB1[15*400+p]=leaky(a3[3]);
        } else {
            #pragma unroll
            for (int o = 0; o < 16; ++o) shB1[o*400+p] = 0.f;
        }
    }
    __syncthreads();

    // ---- phase 3 (MFMA): b2 = leaky(conv3x3(b1)), 16->16, K'=160 ----
    {
        s16x8 A3[5];
        #pragma unroll
        for (int s = 0; s < 5; ++s)
            A3[s] = *(const s16x8*)&wsW2b[col * 160 + s * 32 + lq * 8];
        f32x4 bias3;
        #pragma unroll
        for (int r = 0; r < 4; ++r) bias3[r] = bb2[lq * 4 + r];

        #pragma unroll 1
        for (int g = wv; g < 21; g += 4) {
            const int p  = g * 16 + col;
            const int pc = (p < 324) ? p : 0;
            const int r2 = (pc * 3641) >> 16;      // /18
            const int c2 = pc - r2 * 18;
            const int pbase = r2 * 20 + c2;
            f32x4 c3 = bias3;
            #pragma unroll
            for (int s = 0; s < 5; ++s) {
                const int q = 2 * s + (lq >> 1);
                s16x8 B3;
                if (s == 4 && lq >= 2) {
                    #pragma unroll
                    for (int j = 0; j < 8; ++j) B3[j] = 0;
                } else {
                    const int dy = (q * 11) >> 5;  // q/3 for q<9
                    const int dx = q - 3 * dy;
                    const float* src = &shB1[((lq & 1) * 8) * 400
                                             + pbase + dy * 20 + dx];
                    float f0 = src[0],    f1 = src[400],  f2 = src[800];
                    float f3 = src[1200], f4 = src[1600], f5 = src[2000];
                    float f6 = src[2400], f7 = src[2800];
                    unsigned u0, u1, u2, u3;
                    asm("v_cvt_pk_bf16_f32 %0, %1, %2" : "=v"(u0) : "v"(f0), "v"(f1));
                    asm("v_cvt_pk_bf16_f32 %0, %1, %2" : "=v"(u1) : "v"(f2), "v"(f3));
                    asm("v_cvt_pk_bf16_f32 %0, %1, %2" : "=v"(u2) : "v"(f4), "v"(f5));
                    asm("v_cvt_pk_bf16_f32 %0, %1, %2" : "=v"(u3) : "v"(f6), "v"(f7));
                    union { unsigned u[4]; s16x8 v; } cv;
                    cv.u[0] = u0; cv.u[1] = u1; cv.u[2] = u2; cv.u[3] = u3;
                    B3 = cv.v;
                }
                c3 = __builtin_amdgcn_mfma_f32_16x16x32_bf16(A3[s], B3, c3, 0, 0, 0);
            }
            if (p < 324) {
                const int gh = h0 - 1 + r2, gw = w0 - 1 + c2;
                const bool vimg = ((unsigned)gh < 256u) && ((unsigned)gw < 256u);
                #pragma unroll
                for (int r = 0; r < 4; ++r)
                    shB2[(lq * 4 + r) * 324 + p] = vimg ? leaky(c3[r]) : 0.f;
            }
        }
    }
    __syncthreads();

    // ---- phase 4: beta = sigmoid(conv3x3(b2)) on the 16x16 tile ----
    {
        int r3 = tid >> 4, c3 = tid & 15;
        float a = bb3[0];
        #pragma unroll 4
        for (int ic = 0; ic < 16; ++ic)
            #pragma unroll
            for (int k = 0; k < 9; ++k)
                a += bw3[ic * 9 + k]
                     * shB2[ic * 324 + (r3 + k / 3) * 18 + (c3 + k % 3)];
        betaout[((size_t)b << 16) + ((h0 + r3) << 8) + (w0 + c3)]
            = 1.f / (1.f + expf(-a));
    }
}

// ---------------------------------------------------------------------------
extern "C" void kernel_launch(void* const* d_in, const int* in_sizes, int n_in,
                              void* d_out, int out_size, void* d_ws, size_t ws_size,
                              hipStream_t stream) {
    const float* y    = (const float*)d_in[0];
    const float* mask = (const float*)d_in[1];
    const float* fw1  = (const float*)d_in[2];
    const float* fb1  = (const float*)d_in[3];
    const float* fw2  = (const float*)d_in[4];
    const float* fb2  = (const float*)d_in[5];
    const float* aw1  = (const float*)d_in[6];
    const float* ab1  = (const float*)d_in[7];
    const float* aw2  = (const float*)d_in[8];
    const float* ab2  = (const float*)d_in[9];
    const float* aw3  = (const float*)d_in[10];
    const float* ab3  = (const float*)d_in[11];
    const float* bw1  = (const float*)d_in[12];
    const float* bb1  = (const float*)d_in[13];
    const float* bw2  = (const float*)d_in[14];
    const float* bb2  = (const float*)d_in[15];
    const float* bw3  = (const float*)d_in[16];
    const float* bb3  = (const float*)d_in[17];
    float* out = (float*)d_out;

    char* ws = (char*)d_ws;
    float*    sums  = (float*)ws;                // 1 KB
    unsigned* maxu  = (unsigned*)(ws + 1024);    // 1 KB
    float*    wT1g  = (float*)(ws + 2048);       // 1152 B
    short*    wsW2b = (short*)(ws + 3200);       // 5120 B (ends 8320)
    unsigned* wsW1  = (unsigned*)(ws + 12416);   // 4032 B (ends 16448)
    short*    wsW   = (short*)(ws + 20480);      // 16384 B (ends 36864)
    float*    xc    = (float*)(ws + 65536);      // 4 MB

    kInit<<<1, 256, 0, stream>>>(sums, maxu, bw1, bw2, fw1, fw2,
                                 wT1g, wsW2b, wsW1, wsW);
    kA<<<4096, 256, 0, stream>>>(y, mask, fb1, fb2, wsW1, wsW,
                                 xc, sums, maxu);
    kB<<<1, 256, 0, stream>>>(sums, maxu, aw1, ab1, aw2, ab2, aw3, ab3, out);
    kC<<<2048, 256, 0, stream>>>(xc, wT1g, bb1, wsW2b, bb2, bw3, bb3,
                                 out + 8);
}